// Round 9
// baseline (97.136 us; speedup 1.0000x reference)
//
#include <hip/hip_runtime.h>
#include <math.h>

#define B 128
#define S 32
#define Dm 128
#define NV (B * S)
#define MARGINF 0.3f
#define NBLK 2080

typedef __attribute__((ext_vector_type(8))) short short8;
typedef __attribute__((ext_vector_type(16))) float f32x16;

#define GLOBAL_AS __attribute__((address_space(1)))
#define LDS_AS __attribute__((address_space(3)))

#define FSQRT(x) __builtin_amdgcn_sqrtf(x)   // raw v_sqrt_f32 (~1 ulp)
#define FEXP(x) __expf(x)                    // v_exp_f32 native

// RNE f32 -> bf16 (finite inputs only)
__device__ inline unsigned short f2bf(float f) {
    unsigned u = __float_as_uint(f);
    unsigned r = u + 0x7FFF + ((u >> 16) & 1);
    return (unsigned short)(r >> 16);
}
__device__ inline float bf2f(unsigned short h) {
    return __uint_as_float(((unsigned)h) << 16);
}

// ---------------------------------------------------------------------------
// K1 (prep): one block per tracklet i. Normalizes its 32 vectors, quantizes to
// bf16 (hi only), writes Zn (linear global) + a swizzled LDS copy; computes
// sqv = |z|^2 from the QUANTIZED z (self-consistent: d2 = |z_p - z_q|^2 >= 0),
// then wave 0 computes diagsum[i][p] = sum_q exp(|z_p - z_q|) via MFMA.
// Block 0 also re-zeros the last-block atomic counter (graph-safe reset).
// ---------------------------------------------------------------------------
__global__ __launch_bounds__(256) void prep_kernel(const float* __restrict__ X,
                                                   unsigned short* __restrict__ Zn,
                                                   float* __restrict__ sqv,
                                                   float* __restrict__ diagsum,
                                                   unsigned* __restrict__ cnt) {
    int i = blockIdx.x;
    __shared__ unsigned short zlds[4096];   // 32 rows x 128 bf16, swizzled
    __shared__ float sq_sh[32];
    int t = threadIdx.x;
    if (i == 0 && t == 0) cnt[0] = 0;

    int v = t >> 3;          // vector 0..31
    int s = t & 7;           // 8 lanes per vector
    const float4* row = (const float4*)(X + (((size_t)i * S + v) << 7));

    float4 f[4];
    float ss = 0.f;
#pragma unroll
    for (int k = 0; k < 4; ++k) {
        f[k] = row[k * 8 + s];
        ss += f[k].x * f[k].x + f[k].y * f[k].y + f[k].z * f[k].z + f[k].w * f[k].w;
    }
    ss += __shfl_xor(ss, 1); ss += __shfl_xor(ss, 2); ss += __shfl_xor(ss, 4);
    float inv = 1.0f / fmaxf(FSQRT(ss), 1e-12f);

    float s2 = 0.f;
    unsigned short* zrow = Zn + (((size_t)i * S + v) << 7);
#pragma unroll
    for (int k = 0; k < 4; ++k) {
        int fidx = k * 8 + s;              // float4 index within the row (0..31)
        ushort4 h;
        h.x = f2bf(f[k].x * inv); h.y = f2bf(f[k].y * inv);
        h.z = f2bf(f[k].z * inv); h.w = f2bf(f[k].w * inv);
        float gx = bf2f(h.x), gy = bf2f(h.y), gz = bf2f(h.z), gw = bf2f(h.w);
        s2 += gx * gx + gy * gy + gz * gz + gw * gw;
        *(ushort4*)(zrow + fidx * 4) = h;  // global: linear
        // LDS: 16B chunk c = fidx>>1 goes to slot c^(v&7); 8B half = fidx&1
        int addr = (v << 8) + ((((fidx >> 1) ^ (v & 7))) << 4) + ((fidx & 1) << 3);
        *(ushort4*)((char*)zlds + addr) = h;
    }
    s2 += __shfl_xor(s2, 1); s2 += __shfl_xor(s2, 2); s2 += __shfl_xor(s2, 4);
    if (s == 0) { sqv[(i << 5) + v] = s2; sq_sh[v] = s2; }
    __syncthreads();

    if (t < 64) {   // wave 0: E_ii row sums
        int lq = t & 31, kh = t >> 5, sx = lq & 7;
        f32x16 acc;
#pragma unroll
        for (int r = 0; r < 16; ++r) acc[r] = 0.f;
#pragma unroll
        for (int ks = 0; ks < 8; ++ks) {
            int off = (lq << 8) + (((2 * ks + kh) ^ sx) << 4);
            short8 av = *(const short8*)((char*)zlds + off);
            acc = __builtin_amdgcn_mfma_f32_32x32x16_bf16(av, av, acc, 0, 0, 0);
        }
        float sql = sq_sh[lq];
        float ssum = 0.f;
#pragma unroll
        for (int r = 0; r < 16; ++r) {
            int m = (r & 3) + 8 * (r >> 2) + 4 * kh;
            float d2 = sq_sh[m] + sql - 2.f * acc[r];
            ssum += FEXP(FSQRT(fmaxf(d2, 1e-12f)));
        }
        ssum += __shfl_xor(ssum, 32);
        if (t < 32) diagsum[(i << 5) + lq] = ssum;
    }
}

// ---------------------------------------------------------------------------
// K2 (pair): triangular block (jg, i), i in [0, 4jg+3). Stages panel i + 4
// j-panels (8 KB each) via global_load_lds (linear LDS dest, XOR swizzle on
// the per-lane GLOBAL source; same involution on the ds_read side). Wave w
// handles pair (i, j=4jg+w) when j > i: acc = Zi.Zj^T (col stats in-lane),
// acc2 = Zj.Zi^T (row stats in-lane); fused a/c build + bitonic rank-select
// -> Dmat. Then last-block pattern: threadfence + atomicAdd; the final block
// computes the margin-ranking loss from Dmat (volatile, symmetric-coalesced).
// ---------------------------------------------------------------------------
__global__ __launch_bounds__(256) void pair_kernel(const unsigned short* __restrict__ Zn,
                                                   const float* __restrict__ sqv,
                                                   const float* __restrict__ diagsum,
                                                   const int* __restrict__ tgt,
                                                   float* __restrict__ Dmat,
                                                   unsigned* __restrict__ cnt,
                                                   float* __restrict__ out) {
    // unrank t0 -> (jg, i): start(jg) = 2*jg^2 + jg
    int t0 = blockIdx.x;
    int jg = (int)((sqrtf(8.f * (float)t0 + 1.f) - 1.f) * 0.25f);
    while (jg > 0 && t0 < 2 * jg * jg + jg) --jg;
    while (t0 >= 2 * (jg + 1) * (jg + 1) + (jg + 1)) ++jg;
    int i = t0 - (2 * jg * jg + jg);
    int jbase = jg * 4;

    extern __shared__ unsigned short lds[];   // 5 * 4096 ushort = 40 KB

    int t = threadIdx.x;
    int w = t >> 6;
    int lane = t & 63;

    // ---- staging: 40 segments of 1 KB; wave w owns segs [w*10, w*10+10) ----
    {
        int slot = lane & 15;
        int rhi = lane >> 4;
#pragma unroll
        for (int k = 0; k < 10; ++k) {
            int seg = w * 10 + k;
            int panel = seg >> 3;
            int row = ((seg & 7) << 2) | rhi;
            int vec = (panel == 0) ? i : (jbase + panel - 1);
            const unsigned short* gsrc =
                Zn + ((size_t)vec << 12) + (row << 7) + ((slot ^ (row & 7)) << 3);
            unsigned short* ldst = lds + seg * 512;
            __builtin_amdgcn_global_load_lds((const GLOBAL_AS void*)(const void*)gsrc,
                                             (LDS_AS void*)(void*)ldst, 16, 0, 0);
        }
    }
    __syncthreads();

    int j = jbase + w;
    if (j > i) {
        const unsigned short* Pi = lds;
        const unsigned short* Pj = lds + (w + 1) * 4096;
        int lq = lane & 31;
        int kh = lane >> 5;
        int sx = lq & 7;

        f32x16 acc, acc2;
#pragma unroll
        for (int r = 0; r < 16; ++r) { acc[r] = 0.f; acc2[r] = 0.f; }

#pragma unroll
        for (int ks = 0; ks < 8; ++ks) {
            int off = (lq << 7) + (((2 * ks + kh) ^ sx) << 3);
            short8 av = *(const short8*)(Pi + off);
            short8 bv = *(const short8*)(Pj + off);
            acc  = __builtin_amdgcn_mfma_f32_32x32x16_bf16(av, bv, acc, 0, 0, 0);
            acc2 = __builtin_amdgcn_mfma_f32_32x32x16_bf16(bv, av, acc2, 0, 0, 0);
        }

        float sqi_l = sqv[(i << 5) + lq];
        float sqj_l = sqv[(j << 5) + lq];
        float di = diagsum[(i << 5) + lq];
        float dj = diagsum[(j << 5) + lq];

        float csum = 0.f, cmin = INFINITY, rsum = 0.f, rmin = INFINITY;
#pragma unroll
        for (int r = 0; r < 16; ++r) {
            int m = (r & 3) + 8 * (r >> 2) + 4 * kh;
            float sqim = __shfl(sqi_l, m);
            float sqjm = __shfl(sqj_l, m);
            float d2a = sqim + sqj_l - 2.f * acc[r];    // E[m][lq]
            float ea = FEXP(FSQRT(fmaxf(d2a, 1e-12f)));
            csum += ea; cmin = fminf(cmin, ea);
            float d2b = sqi_l + sqjm - 2.f * acc2[r];   // E[lq][m]
            float eb = FEXP(FSQRT(fmaxf(d2b, 1e-12f)));
            rsum += eb; rmin = fminf(rmin, eb);
        }
        csum += __shfl_xor(csum, 32);
        cmin = fminf(cmin, __shfl_xor(cmin, 32));
        rsum += __shfl_xor(rsum, 32);
        rmin = fminf(rmin, __shfl_xor(rmin, 32));

        float aval = rmin / (di + rsum);
        float cval = cmin / (dj + csum);

        float v = (lane < 32) ? aval : cval;
#pragma unroll
        for (int k = 2; k <= 32; k <<= 1) {
#pragma unroll
            for (int mm = k >> 1; mm >= 1; mm >>= 1) {
                float o = __shfl_xor(v, mm);
                bool asc = ((lq & k) == 0);
                bool upper = (lq & mm) != 0;
                float mn = fminf(v, o), mx = fmaxf(v, o);
                v = (asc == upper) ? mx : mn;
            }
        }
        float ta3 = __shfl(v, 29), ta6 = __shfl(v, 26);
        float tc3 = __shfl(v, 61), tc6 = __shfl(v, 58);

        if (lane == 0) {
            float v_same = fmaxf(ta6, tc6);
            float v_diff = fminf(ta3, tc3);
            float val = (tgt[i] == tgt[j]) ? v_same : v_diff;
            Dmat[i * B + j] = val;
            Dmat[j * B + i] = val;
        }
    }

    // ---- last-block fused final reduction ----
    __syncthreads();                      // all waves alive; Dmat writes drained
    int* flagp = (int*)lds + 256;
    if (t == 0) {
        __threadfence();                  // release: write back local L2
        unsigned old = atomicAdd(cnt, 1u);
        *flagp = (old == NBLK - 1);
    }
    __syncthreads();
    if (*flagp) {
        __threadfence();                  // acquire: invalidate local caches
        float* red = (float*)lds;
        if (t < B) {
            int ti = tgt[t];
            float ap = -INFINITY, an = INFINITY;
            for (int jj = 0; jj < B; ++jj) {
                // D symmetric: D[t][jj] == D[jj][t]; column read is coalesced
                float vdm = (jj == t) ? 0.f
                          : *(volatile const float*)(Dmat + jj * B + t);
                if (tgt[jj] == ti) ap = fmaxf(ap, vdm);
                else an = fminf(an, vdm);
            }
            float term = ap - an + MARGINF;
            red[t] = term > 0.f ? term : 0.f;
        }
        __syncthreads();
        if (t < 64) {
            float r0 = red[t] + red[t + 64];
            r0 += __shfl_down(r0, 32); r0 += __shfl_down(r0, 16);
            r0 += __shfl_down(r0, 8);  r0 += __shfl_down(r0, 4);
            r0 += __shfl_down(r0, 2);  r0 += __shfl_down(r0, 1);
            if (t == 0) out[0] = r0 / (float)B;
        }
    }
}

// ---------------------------------------------------------------------------
extern "C" void kernel_launch(void* const* d_in, const int* in_sizes, int n_in,
                              void* d_out, int out_size, void* d_ws, size_t ws_size,
                              hipStream_t stream) {
    const float* X = (const float*)d_in[0];   // (128, 32, 128) f32
    const int* tgt = (const int*)d_in[1];     // (128,) int
    float* out = (float*)d_out;

    // ws: Zn bf16 1MB | sqv 16KB | diagsum 16KB | Dmat 64KB | cnt 4B
    unsigned short* Zn = (unsigned short*)d_ws;
    float* sqv = (float*)(Zn + (size_t)NV * Dm);
    float* diagsum = sqv + NV;
    float* Dmat = diagsum + NV / S * S;  // = diagsum + 4096
    unsigned* cnt = (unsigned*)(Dmat + B * B);

    prep_kernel<<<B, 256, 0, stream>>>(X, Zn, sqv, diagsum, cnt);
    pair_kernel<<<NBLK, 256, 5 * 4096 * sizeof(unsigned short), stream>>>(
        Zn, sqv, diagsum, tgt, Dmat, cnt, out);
}

// Round 10
// 35.608 us; speedup vs baseline: 2.7279x; 2.7279x over previous
//
#include <hip/hip_runtime.h>
#include <math.h>

#define B 128
#define S 32
#define Dm 128
#define NV (B * S)
#define MARGINF 0.3f
#define NBLK 2080

typedef __attribute__((ext_vector_type(8))) short short8;
typedef __attribute__((ext_vector_type(16))) float f32x16;

#define GLOBAL_AS __attribute__((address_space(1)))
#define LDS_AS __attribute__((address_space(3)))

#define FSQRT(x) __builtin_amdgcn_sqrtf(x)   // raw v_sqrt_f32 (~1 ulp)
#define FEXP(x) __expf(x)                    // native v_exp_f32 path

// RNE f32 -> bf16 (finite inputs only)
__device__ inline unsigned short f2bf(float f) {
    unsigned u = __float_as_uint(f);
    unsigned r = u + 0x7FFF + ((u >> 16) & 1);
    return (unsigned short)(r >> 16);
}
__device__ inline float bf2f(unsigned short h) {
    return __uint_as_float(((unsigned)h) << 16);
}

// ---------------------------------------------------------------------------
// K1 (prep): one block per tracklet i. Normalizes its 32 vectors, quantizes to
// bf16 (hi only), writes Zn (linear global) + a swizzled LDS copy; computes
// sqv = |z|^2 from the QUANTIZED z (self-consistent: d2 = |z_p - z_q|^2 >= 0),
// then wave 0 computes diagsum[i][p] = sum_q exp(|z_p - z_q|) via MFMA.
// ---------------------------------------------------------------------------
__global__ __launch_bounds__(256) void prep_kernel(const float* __restrict__ X,
                                                   unsigned short* __restrict__ Zn,
                                                   float* __restrict__ sqv,
                                                   float* __restrict__ diagsum) {
    int i = blockIdx.x;
    __shared__ unsigned short zlds[4096];   // 32 rows x 128 bf16, swizzled
    __shared__ float sq_sh[32];
    int t = threadIdx.x;

    int v = t >> 3;          // vector 0..31
    int s = t & 7;           // 8 lanes per vector
    const float4* row = (const float4*)(X + (((size_t)i * S + v) << 7));

    float4 f[4];
    float ss = 0.f;
#pragma unroll
    for (int k = 0; k < 4; ++k) {
        f[k] = row[k * 8 + s];
        ss += f[k].x * f[k].x + f[k].y * f[k].y + f[k].z * f[k].z + f[k].w * f[k].w;
    }
    ss += __shfl_xor(ss, 1); ss += __shfl_xor(ss, 2); ss += __shfl_xor(ss, 4);
    float inv = 1.0f / fmaxf(FSQRT(ss), 1e-12f);

    float s2 = 0.f;
    unsigned short* zrow = Zn + (((size_t)i * S + v) << 7);
#pragma unroll
    for (int k = 0; k < 4; ++k) {
        int fidx = k * 8 + s;              // float4 index within the row (0..31)
        ushort4 h;
        h.x = f2bf(f[k].x * inv); h.y = f2bf(f[k].y * inv);
        h.z = f2bf(f[k].z * inv); h.w = f2bf(f[k].w * inv);
        float gx = bf2f(h.x), gy = bf2f(h.y), gz = bf2f(h.z), gw = bf2f(h.w);
        s2 += gx * gx + gy * gy + gz * gz + gw * gw;
        *(ushort4*)(zrow + fidx * 4) = h;  // global: linear
        // LDS: 16B chunk c = fidx>>1 goes to slot c^(v&7); 8B half = fidx&1
        int addr = (v << 8) + ((((fidx >> 1) ^ (v & 7))) << 4) + ((fidx & 1) << 3);
        *(ushort4*)((char*)zlds + addr) = h;
    }
    s2 += __shfl_xor(s2, 1); s2 += __shfl_xor(s2, 2); s2 += __shfl_xor(s2, 4);
    if (s == 0) { sqv[(i << 5) + v] = s2; sq_sh[v] = s2; }
    __syncthreads();

    if (t < 64) {   // wave 0: E_ii row sums
        int lq = t & 31, kh = t >> 5, sx = lq & 7;
        f32x16 acc;
#pragma unroll
        for (int r = 0; r < 16; ++r) acc[r] = 0.f;
#pragma unroll
        for (int ks = 0; ks < 8; ++ks) {
            int off = (lq << 8) + (((2 * ks + kh) ^ sx) << 4);
            short8 av = *(const short8*)((char*)zlds + off);
            acc = __builtin_amdgcn_mfma_f32_32x32x16_bf16(av, av, acc, 0, 0, 0);
        }
        float sql = sq_sh[lq];
        float ssum = 0.f;
#pragma unroll
        for (int r = 0; r < 16; ++r) {
            int m = (r & 3) + 8 * (r >> 2) + 4 * kh;
            float d2 = sq_sh[m] + sql - 2.f * acc[r];
            ssum += FEXP(FSQRT(fmaxf(d2, 1e-12f)));
        }
        ssum += __shfl_xor(ssum, 32);
        if (t < 32) diagsum[(i << 5) + lq] = ssum;
    }
}

// ---------------------------------------------------------------------------
// K2 (pair): triangular block (jg, i), i in [0, 4jg+3). Stages panel i + 4
// j-panels (8 KB each) via global_load_lds (linear LDS dest, XOR swizzle on
// the per-lane GLOBAL source; same involution on the ds_read side). Wave w
// handles pair (i, j=4jg+w) when j > i: acc = Zi.Zj^T (col stats in-lane),
// acc2 = Zj.Zi^T (row stats in-lane); fused a/c build + bitonic rank-select
// -> Dmat[i][j] = Dmat[j][i].
// ---------------------------------------------------------------------------
__global__ __launch_bounds__(256) void pair_kernel(const unsigned short* __restrict__ Zn,
                                                   const float* __restrict__ sqv,
                                                   const float* __restrict__ diagsum,
                                                   const int* __restrict__ tgt,
                                                   float* __restrict__ Dmat) {
    // unrank t0 -> (jg, i): start(jg) = 2*jg^2 + jg
    int t0 = blockIdx.x;
    int jg = (int)((sqrtf(8.f * (float)t0 + 1.f) - 1.f) * 0.25f);
    while (jg > 0 && t0 < 2 * jg * jg + jg) --jg;
    while (t0 >= 2 * (jg + 1) * (jg + 1) + (jg + 1)) ++jg;
    int i = t0 - (2 * jg * jg + jg);
    int jbase = jg * 4;

    extern __shared__ unsigned short lds[];   // 5 * 4096 ushort = 40 KB

    int t = threadIdx.x;
    int w = t >> 6;
    int lane = t & 63;

    // ---- staging: 40 segments of 1 KB; wave w owns segs [w*10, w*10+10) ----
    {
        int slot = lane & 15;
        int rhi = lane >> 4;
#pragma unroll
        for (int k = 0; k < 10; ++k) {
            int seg = w * 10 + k;
            int panel = seg >> 3;
            int row = ((seg & 7) << 2) | rhi;
            int vec = (panel == 0) ? i : (jbase + panel - 1);
            const unsigned short* gsrc =
                Zn + ((size_t)vec << 12) + (row << 7) + ((slot ^ (row & 7)) << 3);
            unsigned short* ldst = lds + seg * 512;
            __builtin_amdgcn_global_load_lds((const GLOBAL_AS void*)(const void*)gsrc,
                                             (LDS_AS void*)(void*)ldst, 16, 0, 0);
        }
    }
    __syncthreads();

    int j = jbase + w;
    if (j <= i) return;       // no further barriers

    const unsigned short* Pi = lds;
    const unsigned short* Pj = lds + (w + 1) * 4096;
    int lq = lane & 31;
    int kh = lane >> 5;
    int sx = lq & 7;

    f32x16 acc, acc2;
#pragma unroll
    for (int r = 0; r < 16; ++r) { acc[r] = 0.f; acc2[r] = 0.f; }

#pragma unroll
    for (int ks = 0; ks < 8; ++ks) {
        int off = (lq << 7) + (((2 * ks + kh) ^ sx) << 3);
        short8 av = *(const short8*)(Pi + off);
        short8 bv = *(const short8*)(Pj + off);
        acc  = __builtin_amdgcn_mfma_f32_32x32x16_bf16(av, bv, acc, 0, 0, 0);
        acc2 = __builtin_amdgcn_mfma_f32_32x32x16_bf16(bv, av, acc2, 0, 0, 0);
    }

    // ---- epilogue: both stat directions via in-lane reg reductions ----
    float sqi_l = sqv[(i << 5) + lq];
    float sqj_l = sqv[(j << 5) + lq];
    float di = diagsum[(i << 5) + lq];
    float dj = diagsum[(j << 5) + lq];

    float csum = 0.f, cmin = INFINITY, rsum = 0.f, rmin = INFINITY;
#pragma unroll
    for (int r = 0; r < 16; ++r) {
        int m = (r & 3) + 8 * (r >> 2) + 4 * kh;
        float sqim = __shfl(sqi_l, m);
        float sqjm = __shfl(sqj_l, m);
        float d2a = sqim + sqj_l - 2.f * acc[r];    // E[m][lq]
        float ea = FEXP(FSQRT(fmaxf(d2a, 1e-12f)));
        csum += ea; cmin = fminf(cmin, ea);
        float d2b = sqi_l + sqjm - 2.f * acc2[r];   // E[lq][m]
        float eb = FEXP(FSQRT(fmaxf(d2b, 1e-12f)));
        rsum += eb; rmin = fminf(rmin, eb);
    }
    csum += __shfl_xor(csum, 32);
    cmin = fminf(cmin, __shfl_xor(cmin, 32));
    rsum += __shfl_xor(rsum, 32);
    rmin = fminf(rmin, __shfl_xor(rmin, 32));

    float aval = rmin / (di + rsum);
    float cval = cmin / (dj + csum);

    // bitonic ascending sort within each 32-lane half: half0 = a, half1 = c
    float v = (lane < 32) ? aval : cval;
#pragma unroll
    for (int k = 2; k <= 32; k <<= 1) {
#pragma unroll
        for (int mm = k >> 1; mm >= 1; mm >>= 1) {
            float o = __shfl_xor(v, mm);
            bool asc = ((lq & k) == 0);
            bool upper = (lq & mm) != 0;
            float mn = fminf(v, o), mx = fmaxf(v, o);
            v = (asc == upper) ? mx : mn;
        }
    }
    // ascending: 3rd largest at lane 29, 6th at lane 26 (per half)
    float ta3 = __shfl(v, 29), ta6 = __shfl(v, 26);
    float tc3 = __shfl(v, 61), tc6 = __shfl(v, 58);

    if (lane == 0) {
        float v_same = fmaxf(ta6, tc6);
        float v_diff = fminf(ta3, tc3);
        float val = (tgt[i] == tgt[j]) ? v_same : v_diff;
        Dmat[i * B + j] = val;
        Dmat[j * B + i] = val;
    }
}

// ---------------------------------------------------------------------------
// K3 (final): hardest positive / hardest negative per row + mean loss.
// ---------------------------------------------------------------------------
__global__ __launch_bounds__(128) void final_kernel(const float* __restrict__ Dmat,
                                                    const int* __restrict__ tgt,
                                                    float* __restrict__ out) {
    int i = threadIdx.x;
    int ti = tgt[i];
    float ap = -INFINITY, an = INFINITY;
    for (int jj = 0; jj < B; ++jj) {
        float v = (jj == i) ? 0.f : Dmat[i * B + jj];
        if (tgt[jj] == ti) ap = fmaxf(ap, v);
        else an = fminf(an, v);
    }
    float term = ap - an + MARGINF;
    term = term > 0.f ? term : 0.f;

    __shared__ float red[128];
    red[i] = term;
    __syncthreads();
    for (int off = 64; off >= 1; off >>= 1) {
        if (i < off) red[i] += red[i + off];
        __syncthreads();
    }
    if (i == 0) out[0] = red[0] / (float)B;
}

// ---------------------------------------------------------------------------
extern "C" void kernel_launch(void* const* d_in, const int* in_sizes, int n_in,
                              void* d_out, int out_size, void* d_ws, size_t ws_size,
                              hipStream_t stream) {
    const float* X = (const float*)d_in[0];   // (128, 32, 128) f32
    const int* tgt = (const int*)d_in[1];     // (128,) int
    float* out = (float*)d_out;

    // ws: Zn bf16 1MB | sqv 16KB | diagsum 16KB | Dmat 64KB
    unsigned short* Zn = (unsigned short*)d_ws;
    float* sqv = (float*)(Zn + (size_t)NV * Dm);
    float* diagsum = sqv + NV;
    float* Dmat = diagsum + NV;

    prep_kernel<<<B, 256, 0, stream>>>(X, Zn, sqv, diagsum);
    pair_kernel<<<NBLK, 256, 5 * 4096 * sizeof(unsigned short), stream>>>(
        Zn, sqv, diagsum, tgt, Dmat);
    final_kernel<<<1, 128, 0, stream>>>(Dmat, tgt, out);
}